// Round 13
// baseline (276.135 us; speedup 1.0000x reference)
//
#include <hip/hip_runtime.h>
#include <cstdint>
#include <cstddef>

#define NT 256
#define LOG2E 1.4426950408889634f

typedef float v2f __attribute__((ext_vector_type(2)));
typedef float v4f __attribute__((ext_vector_type(4)));

#if defined(__has_builtin)
#  if __has_builtin(__builtin_amdgcn_exp2f)
#    define EXP2F(x) __builtin_amdgcn_exp2f(x)
#  else
#    define EXP2F(x) exp2f(x)
#  endif
#else
#  define EXP2F(x) exp2f(x)
#endif

// ---------------- shared-memory layout (float offsets) ----------------
enum {
  OFF_EEGB = 0,       // 8
  OFF_PSAW = 8,       // 16
  OFF_PSAB = 24,      // 8
  OFF_LOCW = 32,      // 24
  OFF_LOCB = 56,      // 8
  OFF_TGTW = 64,      // 8
  OFF_TGTB = 72,      // 8
  OFF_NG   = 80,      // 8
  OFF_NB   = 88,      // 8
  OFF_CINW = 96,      // 192 (q-rows pre-scaled by log2e)
  OFF_CINB = 288,     // 24
  OFF_COUTW= 312,     // 64
  OFF_COUTB= 376,     // 8
  OFF_SINW = 384,     // 192
  OFF_SINB = 576,     // 24
  OFF_SOUTW= 600,     // 64
  OFF_SOUTB= 664,     // 8
  OFF_OINW = 672,     // 192
  OFF_OINB = 864,     // 24
  OFF_OOUTW= 888,     // 64
  OFF_OOUTB= 952,     // 8
  OFF_FC1B = 960,     // 90 -> 1050
  OFF_PE30 = 1052,    // 8
  OFF_PE32 = 1060,    // 8 -> 1068
  OFF_Ebuf = 1068,    // 240
  OFF_Pbuf = 1308,    // 256
  OFF_Sbuf = 1564,    // 256
  OFF_Abuf = 1820,    // 256
  OFF_Lbuf = 2076,    // 256
  OFF_Tbuf = 2332,    // 256 (final q source; then final raw output for fc1)
  OFF_CAT  = 2588,    // 1008 -> 3596
  OFF_QP   = 3596,    // 32 groups x 20 -> 4236
  OFF_K8   = 4236,    // 8 sets x 8h x 36 = 2304 -> 6540
  OFF_V8   = 6540,    // 2304 -> 8844
  OFF_FCO  = 8844,    // 90 -> 8934
  SM_TOTAL = 8936,    // 35744 B -> 4 blocks/CU
  // aliases into K8/V8 region (time-disjoint):
  OFF_EEGW = OFF_K8,            // 672 floats [o][84], dead before phase A
  OFF_KF   = OFF_K8,            // final MHA K: 8h x 132 = 1056
  OFF_VF   = OFF_K8 + 1056,     // final MHA V: 1056
};
// KV set ids: 0=e,1=p,2=s,3=a,4=l (cross-proj), 5=e,6=p,7=a (self-proj)

// phase-B descriptor: flags 1=reset cat, 2=store cat, 4=save carry, 8=add carry
struct BD { short qoff, Lq, set, sel, dst, flags; };
static __device__ const BD g_bd[18] = {
  {OFF_Ebuf, 30, 1, 0,  0, 1},    // cross(e,p)   reset
  {OFF_Ebuf, 30, 3, 0,  0, 0},    // cross(e,a)
  {OFF_Ebuf, 30, 4, 0,  0, 0},    // cross(e,l)
  {OFF_Ebuf, 30, 5, 1,  0, 0},    // selfa(e)
  {OFF_Ebuf, 30, 2, 0,  0, 2},    // cross(e,s)   store@0
  {OFF_Pbuf, 32, 0, 0, 30, 1},    // cross(p,e)   reset
  {OFF_Pbuf, 32, 3, 0, 30, 0},    // cross(p,a)
  {OFF_Pbuf, 32, 4, 0, 30, 0},    // cross(p,l)
  {OFF_Pbuf, 32, 6, 1, 30, 0},    // selfa(p)
  {OFF_Pbuf, 32, 2, 0, 30, 2},    // cross(p,s)   store@30
  {OFF_Sbuf, 32, 0, 0, 94, 1},    // cross(s,e)   reset
  {OFF_Sbuf, 32, 1, 0, 94, 0},    // cross(s,p)
  {OFF_Sbuf, 32, 3, 0, 94, 0},    // cross(s,a)
  {OFF_Sbuf, 32, 4, 0, 94, 2|4},  // cross(s,l)   carry-save, store@94
  {OFF_Abuf, 32, 0, 0, 62, 1},    // cross(a,e)   reset
  {OFF_Abuf, 32, 1, 0, 62, 0},    // cross(a,p)
  {OFF_Abuf, 32, 2, 0, 62, 0},    // cross(a,s)
  {OFF_Abuf, 32, 7, 1, 62, 2|8},  // selfa(a)     carry-add, store@62
};

__device__ __forceinline__ float hsum4(v4f a) {
  v2f t = a.xy + a.zw;
  return t.x + t.y;
}

__device__ __forceinline__ float dot8(const float* __restrict__ x,
                                      const float* __restrict__ w, float bias) {
  v4f xa = *(const v4f*)x, xb = *(const v4f*)(x + 4);
  return bias + hsum4(xa * *(const v4f*)w + xb * *(const v4f*)(w + 4));
}

// 1-row attention (no max pass: softmax shift-invariant, scores bounded)
// + out-proj + LayerNorm via LDS exchange, zero bpermutes.
template<int LK>
__device__ __forceinline__ float attn1_nv(float q, const float* Kp, const float* Vp,
                                          float* qslot, int h, const float* sm,
                                          int woutO, int boutO, float gg, float bb) {
  v4f l4 = {0.f,0.f,0.f,0.f}, A4 = {0.f,0.f,0.f,0.f};
  #pragma unroll
  for (int t = 0; t < (LK >> 2); t++) {
    v4f kk = *(const v4f*)(Kp + 4 * t);
    v4f vv = *(const v4f*)(Vp + 4 * t);
    v4f sc = kk * q;
    v4f ee = { EXP2F(sc.x), EXP2F(sc.y), EXP2F(sc.z), EXP2F(sc.w) };
    l4 += ee; A4 += ee * vv;
  }
  if constexpr ((LK & 3) != 0) {  // tail == 2 in all shapes used
    v2f kk = *(const v2f*)(Kp + (LK & ~3));
    v2f vv = *(const v2f*)(Vp + (LK & ~3));
    v2f sc = kk * q;
    v2f ee = { EXP2F(sc.x), EXP2F(sc.y) };
    l4.xy = l4.xy + ee; A4.xy = A4.xy + ee * vv;
  }
  float ov = hsum4(A4) * __builtin_amdgcn_rcpf(hsum4(l4));
  // intra-8-lane-group exchange (same wave lockstep -> program order, no barrier)
  qslot[h] = ov;
  v4f c0 = *(const v4f*)qslot, c1 = *(const v4f*)(qslot + 4);
  v4f woa = *(const v4f*)(sm + woutO + h * 8), wob = *(const v4f*)(sm + woutO + h * 8 + 4);
  float a = sm[boutO + h] + hsum4(c0 * woa + c1 * wob);
  qslot[h] = a;
  c0 = *(const v4f*)qslot; c1 = *(const v4f*)(qslot + 4);
  float mu = hsum4(c0 + c1) * 0.125f;
  v4f e0 = c0 - mu, e1 = c1 - mu;
  float var = hsum4(e0 * e0 + e1 * e1) * 0.125f;
  return fmaf((a - mu) * rsqrtf(var + 1e-5f), gg, bb);
}

__global__ __launch_bounds__(NT, 4) void cmt_kernel(
    const float* __restrict__ eeg, const float* __restrict__ pupil,
    const float* __restrict__ speech, const float* __restrict__ action,
    const float* __restrict__ location, const float* __restrict__ tgt,
    const float* __restrict__ eeg_w, const float* __restrict__ eeg_b,
    const float* __restrict__ psa_w, const float* __restrict__ psa_b,
    const float* __restrict__ loc_w, const float* __restrict__ loc_b,
    const float* __restrict__ tgt_w, const float* __restrict__ tgt_b,
    const float* __restrict__ ng, const float* __restrict__ nb,
    const float* __restrict__ cin_w, const float* __restrict__ cin_b,
    const float* __restrict__ cout_w, const float* __restrict__ cout_b,
    const float* __restrict__ sin_w, const float* __restrict__ sin_b,
    const float* __restrict__ sout_w, const float* __restrict__ sout_b,
    const float* __restrict__ oin_w, const float* __restrict__ oin_b,
    const float* __restrict__ oout_w, const float* __restrict__ oout_b,
    const float* __restrict__ fc1_w, const float* __restrict__ fc1_b,
    float* __restrict__ out)
{
  __shared__ __align__(16) float sm[SM_TOTAL];
  const int tid = threadIdx.x;
  const int b = blockIdx.x;

#define CP(off, p, n) for (int i = tid; i < (n); i += NT) sm[(off)+i] = (p)[i]
#define CPQ(off, p, n, nq) for (int i = tid; i < (n); i += NT) sm[(off)+i] = (p)[i] * ((i < (nq)) ? LOG2E : 1.0f)

  // ---------- phase 0: stage weights ----------
  for (int i = tid; i < 640; i += NT) sm[OFF_EEGW + (i / 80) * 84 + (i % 80)] = eeg_w[i];
  CP(OFF_EEGB, eeg_b, 8);
  CP(OFF_PSAW, psa_w, 16);   CP(OFF_PSAB, psa_b, 8);
  CP(OFF_LOCW, loc_w, 24);   CP(OFF_LOCB, loc_b, 8);
  CP(OFF_TGTW, tgt_w, 8);    CP(OFF_TGTB, tgt_b, 8);
  CP(OFF_NG, ng, 8);         CP(OFF_NB, nb, 8);
  CPQ(OFF_CINW, cin_w, 192, 64);  CPQ(OFF_CINB, cin_b, 24, 8);
  CP(OFF_COUTW, cout_w, 64); CP(OFF_COUTB, cout_b, 8);
  CPQ(OFF_SINW, sin_w, 192, 64);  CPQ(OFF_SINB, sin_b, 24, 8);
  CP(OFF_SOUTW, sout_w, 64); CP(OFF_SOUTB, sout_b, 8);
  CPQ(OFF_OINW, oin_w, 192, 64);  CPQ(OFF_OINB, oin_b, 24, 8);
  CP(OFF_OOUTW, oout_w, 64); CP(OFF_OOUTB, oout_b, 8);
  CP(OFF_FC1B, fc1_b, 90);
  if (tid < 16) {
    const float divs[4] = {1.f, 0.1f, 0.01f, 0.001f};
    float pos = (tid < 8) ? 30.f : 32.f;
    int e = tid & 7;
    float x = pos * divs[e >> 1];
    float v = (e & 1) ? cosf(x) : sinf(x);
    sm[((tid < 8) ? OFF_PE30 : OFF_PE32) + e] = v;
  }
  __syncthreads();

  // ---------- phase 1: convs + positional encoding ----------
  if (tid < 240) {  // eeg conv2d -> e[30][8]
    int w = tid >> 3, o = tid & 7;
    const float* ep = eeg + (size_t)b * 4720 + 4 * w;
    const float* wr = sm + OFF_EEGW + o * 84;
    v4f acc4 = {0.f, 0.f, 0.f, 0.f};
    #pragma unroll
    for (int t = 0; t < 20; t++) {
      int ik0 = 2 * t, ik1 = 2 * t + 1;
      float2 x0 = *(const float2*)(ep + (ik0 / 20) * 2360 + (ik0 % 20) * 118);
      float2 x1 = *(const float2*)(ep + (ik1 / 20) * 2360 + (ik1 % 20) * 118);
      v4f xv = {x0.x, x0.y, x1.x, x1.y};
      acc4 += xv * *(const v4f*)(wr + 4 * t);
    }
    sm[OFF_Ebuf + w * 8 + o] = hsum4(acc4) + sm[OFF_EEGB + o] + sm[OFF_PE30 + o];
  }
  {  // conv1d k=1 pad=1 -> length-32 sequences, + pe32
    int t = tid >> 3, o = tid & 7;
    bool inb = (t >= 1 && t <= 30);
    int ti = t - 1;
    float pe = sm[OFF_PE32 + o];
    float w0 = sm[OFF_PSAW + 2 * o], w1 = sm[OFF_PSAW + 2 * o + 1];
    float pb = sm[OFF_PSAB + o];
    float vp = pb, vs = pb, va = pb;
    float vl = sm[OFF_LOCB + o], vt = sm[OFF_TGTB + o];
    if (inb) {
      const float* pp = pupil    + (size_t)b * 60 + ti;
      const float* sp = speech   + (size_t)b * 60 + ti;
      const float* ap = action   + (size_t)b * 60 + ti;
      const float* lp = location + (size_t)b * 90 + ti;
      vp = fmaf(pp[0], w0, fmaf(pp[30], w1, vp));
      vs = fmaf(sp[0], w0, fmaf(sp[30], w1, vs));
      va = fmaf(ap[0], w0, fmaf(ap[30], w1, va));
      vl = fmaf(lp[0],  sm[OFF_LOCW + 3 * o],     vl);
      vl = fmaf(lp[30], sm[OFF_LOCW + 3 * o + 1], vl);
      vl = fmaf(lp[60], sm[OFF_LOCW + 3 * o + 2], vl);
      vt = fmaf(tgt[(size_t)b * 30 + ti], sm[OFF_TGTW + o], vt);
    }
    sm[OFF_Pbuf + tid] = vp + pe;
    sm[OFF_Sbuf + tid] = vs + pe;
    sm[OFF_Abuf + tid] = va + pe;
    sm[OFF_Lbuf + tid] = vl + pe;
    sm[OFF_Tbuf + tid] = vt + pe;
  }
  __syncthreads();

  const int qi = tid >> 3, h = tid & 7;
  float* qslot = sm + OFF_QP + qi * 20;

  // ---------- phase A: ALL 8 K/V sets, weights hoisted (scoped) ----------
  {
    const int r = qi;  // 0..31
    v4f cka = *(const v4f*)(sm + OFF_CINW + 64 + h * 8), ckb = *(const v4f*)(sm + OFF_CINW + 68 + h * 8);
    v4f cva = *(const v4f*)(sm + OFF_CINW + 128 + h * 8), cvb = *(const v4f*)(sm + OFF_CINW + 132 + h * 8);
    float cbk = sm[OFF_CINB + 8 + h], cbv = sm[OFF_CINB + 16 + h];
#define KV1(srcO, set, wka, wkb, wva, wvb, bk, bv) { \
    v4f xa = *(const v4f*)(sm + (srcO) + r * 8); \
    v4f xb = *(const v4f*)(sm + (srcO) + r * 8 + 4); \
    sm[OFF_K8 + (set) * 288 + h * 36 + r] = (bk) + hsum4(xa * (wka) + xb * (wkb)); \
    sm[OFF_V8 + (set) * 288 + h * 36 + r] = (bv) + hsum4(xa * (wva) + xb * (wvb)); }
    if (r < 30) KV1(OFF_Ebuf, 0, cka, ckb, cva, cvb, cbk, cbv);
    KV1(OFF_Pbuf, 1, cka, ckb, cva, cvb, cbk, cbv);
    KV1(OFF_Sbuf, 2, cka, ckb, cva, cvb, cbk, cbv);
    KV1(OFF_Abuf, 3, cka, ckb, cva, cvb, cbk, cbv);
    KV1(OFF_Lbuf, 4, cka, ckb, cva, cvb, cbk, cbv);
    v4f ska = *(const v4f*)(sm + OFF_SINW + 64 + h * 8), skb = *(const v4f*)(sm + OFF_SINW + 68 + h * 8);
    v4f sva = *(const v4f*)(sm + OFF_SINW + 128 + h * 8), svb = *(const v4f*)(sm + OFF_SINW + 132 + h * 8);
    float sbk = sm[OFF_SINB + 8 + h], sbv = sm[OFF_SINB + 16 + h];
    if (r < 30) KV1(OFF_Ebuf, 5, ska, skb, sva, svb, sbk, sbv);
    KV1(OFF_Pbuf, 6, ska, skb, sva, svb, sbk, sbv);
    KV1(OFF_Abuf, 7, ska, skb, sva, svb, sbk, sbv);
#undef KV1
  }
  __syncthreads();

  // ---------- phase B: 18 MHAs as a descriptor loop (small code, barrier-free) ----------
  {
    const float gg = sm[OFF_NG + h], bb = sm[OFF_NB + h];
    float cat = 0.f, carry = 0.f;
    #pragma unroll 1
    for (int mi = 0; mi < 18; mi++) {
      const BD d = g_bd[mi];
      if (qi < d.Lq) {
        const int winO  = d.sel ? OFF_SINW  : OFF_CINW;
        const int binO  = d.sel ? OFF_SINB  : OFF_CINB;
        const int woutO = d.sel ? OFF_SOUTW : OFF_COUTW;
        const int boutO = d.sel ? OFF_SOUTB : OFF_COUTB;
        float q = dot8(sm + d.qoff + qi * 8, sm + winO + h * 8, sm[binO + h]);
        const float* Kp = sm + OFF_K8 + d.set * 288 + h * 36;
        const float* Vp = sm + OFF_V8 + d.set * 288 + h * 36;
        bool lk30 = (d.set == 0) | (d.set == 5);
        float nv = lk30 ? attn1_nv<30>(q, Kp, Vp, qslot, h, sm, woutO, boutO, gg, bb)
                        : attn1_nv<32>(q, Kp, Vp, qslot, h, sm, woutO, boutO, gg, bb);
        if (d.flags & 1) cat = 0.f;
        cat += nv;
        if (d.flags & 4) carry = nv;
        if (d.flags & 8) cat += carry;
        if (d.flags & 2) sm[OFF_CAT + (d.dst + qi) * 8 + h] = cat;
      }
    }
  }
  __syncthreads();

  // ---------- final MHA kv-proj of CAT (126 rows), weights hoisted (scoped) ----------
  {
    v4f fka = *(const v4f*)(sm + OFF_OINW + 64 + h * 8), fkb = *(const v4f*)(sm + OFF_OINW + 68 + h * 8);
    v4f fva = *(const v4f*)(sm + OFF_OINW + 128 + h * 8), fvb = *(const v4f*)(sm + OFF_OINW + 132 + h * 8);
    float fbk = sm[OFF_OINB + 8 + h], fbv = sm[OFF_OINB + 16 + h];
    for (int r = qi; r < 126; r += 32) {
      v4f xa = *(const v4f*)(sm + OFF_CAT + r * 8);
      v4f xb = *(const v4f*)(sm + OFF_CAT + r * 8 + 4);
      sm[OFF_KF + h * 132 + r] = fbk + hsum4(xa * fka + xb * fkb);
      sm[OFF_VF + h * 132 + r] = fbv + hsum4(xa * fva + xb * fvb);
    }
  }
  __syncthreads();

  // ---------- final attention (Lk=126, 1 row/thread, exchange-based out-proj) ----------
  {
    float qf = dot8(sm + OFF_Tbuf + qi * 8, sm + OFF_OINW + h * 8, sm[OFF_OINB + h]);
    const float* Kp = sm + OFF_KF + h * 132;
    const float* Vp = sm + OFF_VF + h * 132;
    v4f l4 = {0.f,0.f,0.f,0.f}, A4 = {0.f,0.f,0.f,0.f};
    #pragma unroll
    for (int t = 0; t < 31; t++) {
      v4f kk = *(const v4f*)(Kp + 4 * t);
      v4f vv = *(const v4f*)(Vp + 4 * t);
      v4f sc = kk * qf;
      v4f ee = { EXP2F(sc.x), EXP2F(sc.y), EXP2F(sc.z), EXP2F(sc.w) };
      l4 += ee; A4 += ee * vv;
    }
    {
      v2f kk = *(const v2f*)(Kp + 124);
      v2f vv = *(const v2f*)(Vp + 124);
      v2f sc = kk * qf;
      v2f ee = { EXP2F(sc.x), EXP2F(sc.y) };
      l4.xy = l4.xy + ee; A4.xy = A4.xy + ee * vv;
    }
    float ov = hsum4(A4) * __builtin_amdgcn_rcpf(hsum4(l4));
    qslot[h] = ov;
    v4f c0 = *(const v4f*)qslot, c1 = *(const v4f*)(qslot + 4);
    v4f woa = *(const v4f*)(sm + OFF_OOUTW + h * 8), wob = *(const v4f*)(sm + OFF_OOUTW + h * 8 + 4);
    float a = sm[OFF_OOUTB + h] + hsum4(c0 * woa + c1 * wob);
    sm[OFF_Tbuf + qi * 8 + h] = a;  // wave-lockstep: qf read precedes this store
  }
  __syncthreads();

  // ---------- fc1 (2 threads per output) + channel softmax ----------
  if (tid < 180) {
    int j = tid >> 1, p = tid & 1;
    const v4f* w4 = (const v4f*)(fc1_w + j * 256);
    const v4f* o4 = (const v4f*)(sm + OFF_Tbuf);
    v4f acc4 = {0.f, 0.f, 0.f, 0.f};
    #pragma unroll 8
    for (int c = p; c < 64; c += 2) acc4 += o4[c] * w4[c];
    float acc = hsum4(acc4);
    acc += __shfl_xor(acc, 1);
    if (p == 0) sm[OFF_FCO + j] = acc + sm[OFF_FC1B + j];
  }
  __syncthreads();
  if (tid < 30) {
    float x0 = sm[OFF_FCO + 3 * tid], x1 = sm[OFF_FCO + 3 * tid + 1], x2 = sm[OFF_FCO + 3 * tid + 2];
    float m = fmaxf(x0, fmaxf(x1, x2));
    float e0 = __expf(x0 - m), e1 = __expf(x1 - m), e2 = __expf(x2 - m);
    float inv = __builtin_amdgcn_rcpf(e0 + e1 + e2);
    float* op = out + (size_t)b * 90;
    op[tid]      = e0 * inv;
    op[30 + tid] = e1 * inv;
    op[60 + tid] = e2 * inv;
  }
#undef CP
#undef CPQ
}

extern "C" void kernel_launch(void* const* d_in, const int* in_sizes, int n_in,
                              void* d_out, int out_size, void* d_ws, size_t ws_size,
                              hipStream_t stream) {
  (void)n_in; (void)out_size; (void)d_ws; (void)ws_size;
  int B = in_sizes[0] / 4720;  // eeg = (B,2,20,118)
  cmt_kernel<<<B, NT, 0, stream>>>(
      (const float*)d_in[0],  (const float*)d_in[1],  (const float*)d_in[2],
      (const float*)d_in[3],  (const float*)d_in[4],  (const float*)d_in[5],
      (const float*)d_in[6],  (const float*)d_in[7],  (const float*)d_in[8],
      (const float*)d_in[9],  (const float*)d_in[10], (const float*)d_in[11],
      (const float*)d_in[12], (const float*)d_in[13], (const float*)d_in[14],
      (const float*)d_in[15], (const float*)d_in[16], (const float*)d_in[17],
      (const float*)d_in[18], (const float*)d_in[19], (const float*)d_in[20],
      (const float*)d_in[21], (const float*)d_in[22], (const float*)d_in[23],
      (const float*)d_in[24], (const float*)d_in[25], (const float*)d_in[26],
      (const float*)d_in[27], (const float*)d_in[28], (const float*)d_in[29],
      (float*)d_out);
}